// Round 1
// baseline (31785.651 us; speedup 1.0000x reference)
//
#include <hip/hip_runtime.h>
#include <cstdint>
#include <cstddef>

// ============================================================================
// QuantGRU on MI355X — round 0 (correctness-first, structurally sound)
//
// Pipeline (all on `stream`, graph-capturable):
//   memset ws slots -> absmax(x,W,R,bx,br) -> quantize R into MFMA-B frags
//   -> quantize biases -> Wx GEMM pass1 (global |M| max, int-exact fp32 FMA)
//   -> Wx GEMM pass2 (writes int8 Wxq in recurrent-kernel fragment order,
//      into the TAIL of d_out; write ptr of recurrent output never catches
//      the read ptr: overlap needs t > 1024)
//   -> single-workgroup recurrent kernel (1024 thr, 1 CU):
//        per step: i8 MFMA GEMM (R in 48 B-frag VGPRs, h int8 in padded LDS)
//        + 8 block-reduction rounds for the per-tensor fake-quant scales
//        + in-register gates (z/r/n triple per thread via C-layout col align)
// ============================================================================

typedef int   v4i __attribute__((ext_vector_type(4)));
typedef float v4f __attribute__((ext_vector_type(4)));

#define T_STEPS 1024
#define OUT_MAIN_FLOATS (1024*64*256)          // 16,777,216
#define WXQ_BYTES (1024LL*3*16384)             // 50,331,648
#define WXQ_DOUT_OFF 16842752                  // out_bytes(67,174,400) - WXQ_BYTES

__device__ __forceinline__ float clamp128(float x) {
  return fminf(fmaxf(x, -128.0f), 127.0f);
}
__device__ __forceinline__ int permj(int j) {           // haste row -> pt row
  return j < 256 ? j + 256 : (j < 512 ? j - 256 : j);
}
__device__ __forceinline__ float wave_amax(float v) {
  #pragma unroll
  for (int m = 1; m <= 32; m <<= 1) v = fmaxf(v, __shfl_xor(v, m, 64));
  return v;
}
__device__ __forceinline__ int wave_imax(int v) {
  #pragma unroll
  for (int m = 1; m <= 32; m <<= 1) v = max(v, __shfl_xor(v, m, 64));
  return v;
}
__device__ __forceinline__ float sigmoidf_(float x) {
  return __fdividef(1.0f, 1.0f + __expf(-x));
}
__device__ __forceinline__ float tanhf_(float x) {
  float e = __expf(-2.0f * fabsf(x));
  float t = __fdividef(1.0f - e, 1.0f + e);
  return copysignf(t, x);
}

// ---------------- absmax over a float tensor (n4 = n/4) ----------------
__global__ void k_absmax(const float* __restrict__ p, int n4, unsigned* slot) {
  int i = blockIdx.x * blockDim.x + threadIdx.x;
  int stride = gridDim.x * blockDim.x;
  const v4f* p4 = (const v4f*)p;
  float m = 0.0f;
  for (; i < n4; i += stride) {
    v4f v = p4[i];
    m = fmaxf(m, fmaxf(fmaxf(fabsf(v[0]), fabsf(v[1])),
                       fmaxf(fabsf(v[2]), fabsf(v[3]))));
  }
  m = wave_amax(m);
  if ((threadIdx.x & 63) == 0) atomicMax(slot, __float_as_uint(m));
}

// ---------------- R -> int8 MFMA B-fragments ----------------
// layout byte addr = ((ct*4+kc)*64 + lane)*16 + byte ; value BR[k][n],
// n = ct*16 + (lane&15), k = kc*64 + (lane>>4)*16 + byte.  R[k][n] =
// weight_hh[permj(n)][k].  one thread per packed dword (4 bytes).
__global__ void k_brfrag(const float* __restrict__ whh,
                         const unsigned* __restrict__ slots,
                         signed char* __restrict__ brf) {
  int id = blockIdx.x * 256 + threadIdx.x;   // 0..49151
  float s_R = fmaxf(__uint_as_float(slots[2]) / 127.0f, 1e-8f);
  int bq   = id & 3;
  int lane = (id >> 2) & 63;
  int kc   = (id >> 8) & 3;
  int ct   = id >> 10;
  int n = ct * 16 + (lane & 15);
  int k = kc * 64 + (lane >> 4) * 16 + bq * 4;
  const float* src = whh + permj(n) * 256 + k;
  int b0 = ((int)clamp128(rintf(src[0] / s_R))) & 255;
  int b1 = ((int)clamp128(rintf(src[1] / s_R))) & 255;
  int b2 = ((int)clamp128(rintf(src[2] / s_R))) & 255;
  int b3 = ((int)clamp128(rintf(src[3] / s_R))) & 255;
  ((int*)brf)[id] = b0 | (b1 << 8) | (b2 << 16) | (b3 << 24);
}

// ---------------- biases: reorder + fake-quant (dequantized fp32) ----------
__global__ void k_bias(const float* __restrict__ bih, const float* __restrict__ bhh,
                       const unsigned* __restrict__ slots, float* __restrict__ bqo) {
  int j = threadIdx.x;               // 0..767
  float s_bx = fmaxf(__uint_as_float(slots[3]) / 127.0f, 1e-8f);
  float s_br = fmaxf(__uint_as_float(slots[4]) / 127.0f, 1e-8f);
  int pr = permj(j);
  bqo[j]       = s_bx * clamp128(rintf(bih[pr] / s_bx));
  bqo[768 + j] = s_br * clamp128(rintf(bhh[pr] / s_br));
}

// ---------------- Wx GEMM (both passes) ----------------
// C[tb][j] = sum_i qx(x[tb][i]) * qw(W[i][j]),  W[i][j]=wih[permj(j)][i].
// int-valued fp32 FMA: |products|<=16384, |sums|<=4.2e6 < 2^24 -> EXACT,
// order-independent -> pass1/pass2 deterministic-identical.
// mode 0: atomicMax global |C| ; mode 1: write int8 Wxq in k_recur frag order.
__global__ __launch_bounds__(256) void k_wx_gemm(
    const float* __restrict__ x, const float* __restrict__ wih,
    unsigned* __restrict__ slots, signed char* __restrict__ wxq, int mode) {
  __shared__ float At[32][64];     // [k][row]
  __shared__ float Bt[32][68];     // [k][j] (+4 pad)
  int t  = blockIdx.y;
  int j0 = blockIdx.x * 64;
  int tid = threadIdx.x;
  int tx = tid & 15, ty = tid >> 4;
  float s_x = fmaxf(__uint_as_float(slots[0]) / 127.0f, 1e-8f);
  float s_W = fmaxf(__uint_as_float(slots[1]) / 127.0f, 1e-8f);
  const float* xrow = x + t * 16384;
  float acc[4][4] = {};
  int kq = tid & 7, r0 = tid >> 3;       // A staging map
  int jj = tid >> 2, kq2 = tid & 3;      // B staging map
  int prj = permj(j0 + jj);
  for (int k0 = 0; k0 < 256; k0 += 32) {
    #pragma unroll
    for (int rr = 0; rr < 2; ++rr) {
      int row = r0 + rr * 32;
      v4f v = *(const v4f*)(xrow + row * 256 + k0 + kq * 4);
      #pragma unroll
      for (int c = 0; c < 4; ++c) At[kq * 4 + c][row] = clamp128(rintf(v[c] / s_x));
    }
    {
      const float* wr_ = wih + prj * 256 + k0 + kq2 * 8;
      v4f w1 = *(const v4f*)(wr_);
      v4f w2 = *(const v4f*)(wr_ + 4);
      #pragma unroll
      for (int c = 0; c < 4; ++c) {
        Bt[kq2 * 8 + c][jj]     = clamp128(rintf(w1[c] / s_W));
        Bt[kq2 * 8 + 4 + c][jj] = clamp128(rintf(w2[c] / s_W));
      }
    }
    __syncthreads();
    #pragma unroll 8
    for (int kk = 0; kk < 32; ++kk) {
      v4f a = *(const v4f*)&At[kk][ty * 4];
      v4f b = *(const v4f*)&Bt[kk][tx * 4];
      #pragma unroll
      for (int rr = 0; rr < 4; ++rr)
        #pragma unroll
        for (int cc = 0; cc < 4; ++cc)
          acc[rr][cc] = fmaf(a[rr], b[cc], acc[rr][cc]);
    }
    __syncthreads();
  }
  if (mode == 0) {
    float m = 0.0f;
    #pragma unroll
    for (int rr = 0; rr < 4; ++rr)
      #pragma unroll
      for (int cc = 0; cc < 4; ++cc) m = fmaxf(m, fabsf(acc[rr][cc]));
    m = wave_amax(m);
    if ((tid & 63) == 0) atomicMax((int*)(slots + 5), (int)m);
  } else {
    float maxMf = (float)((int)slots[5]);
    float s_xW = s_x * s_W;
    float s_wx = fmaxf(s_xW * maxMf / 127.0f, 1e-8f);
    #pragma unroll
    for (int rr = 0; rr < 4; ++rr)
      #pragma unroll
      for (int cc = 0; cc < 4; ++cc) {
        float qf = clamp128(rintf((s_xW * acc[rr][cc]) / s_wx));
        int b  = ty * 4 + rr;
        int jg = j0 + tx * 4 + cc;
        int p = jg >> 8, jr = jg & 255;
        int ww = jr >> 4, ccl = jr & 15;
        int rt = b >> 4, lh2 = (b >> 2) & 3, rg = b & 3;
        int tid6 = ww * 64 + lh2 * 16 + ccl;
        wxq[(size_t)(t * 3 + p) * 16384 + tid6 * 16 + rt * 4 + rg] = (signed char)(int)qf;
      }
  }
}

// ---------------- block reductions for k_recur ----------------
template <int NV>
__device__ __forceinline__ void bredmax(float* v, float (*rf)[4], int w, int lane) {
  #pragma unroll
  for (int c = 0; c < NV; ++c) v[c] = wave_amax(v[c]);
  if (lane == 0) {
    #pragma unroll
    for (int c = 0; c < NV; ++c) rf[w][c] = v[c];
  }
  __syncthreads();
  #pragma unroll
  for (int c = 0; c < NV; ++c) {
    float r = rf[0][c];
    #pragma unroll
    for (int i = 1; i < 16; ++i) r = fmaxf(r, rf[i][c]);
    v[c] = r;
  }
}
__device__ __forceinline__ int bredmax_i(int x, int* ri, int w, int lane) {
  x = wave_imax(x);
  if (lane == 0) ri[w] = x;
  __syncthreads();
  int r = ri[0];
  #pragma unroll
  for (int i = 1; i < 16; ++i) r = max(r, ri[i]);
  return r;
}

#define MFMA_I8(a, b, c) __builtin_amdgcn_mfma_i32_16x16x64_i8(a, b, c, 0, 0, 0)

// ---------------- the serial recurrence: ONE workgroup, one CU -------------
__global__ __launch_bounds__(1024) void k_recur(
    const signed char* __restrict__ wxq, const signed char* __restrict__ brf,
    const float* __restrict__ bq, const unsigned* __restrict__ slots,
    const float* __restrict__ h0p, float* __restrict__ out) {
  __shared__ signed char ah[64 * 272];   // int8 h, row stride 272 (bank pad)
  __shared__ float redf[2][16][4];
  __shared__ int   redi[2][16];

  const int tid = threadIdx.x;
  const int lane = tid & 63;
  const int w = tid >> 6;          // wave 0..15  -> ct triple {w, w+16, w+32}
  const int cl = lane & 15;
  const int lh = lane >> 4;        // quad 0..3
  const int j = w * 16 + cl;       // this thread's column (0..255)

  float s_x = fmaxf(__uint_as_float(slots[0]) / 127.0f, 1e-8f);
  float s_W = fmaxf(__uint_as_float(slots[1]) / 127.0f, 1e-8f);
  float s_R = fmaxf(__uint_as_float(slots[2]) / 127.0f, 1e-8f);
  float maxM0 = (float)((int)slots[5]);
  float s_wx = fmaxf(s_x * s_W * maxM0 / 127.0f, 1e-8f);

  float bxz = bq[j], bxr = bq[j + 256], bxn = bq[j + 512];
  float brz = bq[768 + j], brr = bq[1024 + j], brn = bq[1280 + j];

  // R as MFMA-B fragments, resident in VGPRs for the whole kernel (48 regs)
  v4i Bz[4], Br[4], Bn[4];
  #pragma unroll
  for (int kc = 0; kc < 4; ++kc) {
    Bz[kc] = *(const v4i*)(brf + (((w)*4      + kc) * 64 + lane) * 16);
    Br[kc] = *(const v4i*)(brf + (((w + 16)*4 + kc) * 64 + lane) * 16);
    Bn[kc] = *(const v4i*)(brf + (((w + 32)*4 + kc) * 64 + lane) * 16);
  }

  float h[4][4];
  #pragma unroll
  for (int rt = 0; rt < 4; ++rt)
    #pragma unroll
    for (int rg = 0; rg < 4; ++rg)
      h[rt][rg] = h0p[(rt * 16 + lh * 4 + rg) * 256 + j];

  int rnd = 0;
  float sh;   // current h quant scale (carried across steps)
  {
    float m = 0.0f;
    #pragma unroll
    for (int rt = 0; rt < 4; ++rt)
      #pragma unroll
      for (int rg = 0; rg < 4; ++rg) m = fmaxf(m, fabsf(h[rt][rg]));
    float vv[1] = {m};
    bredmax<1>(vv, redf[(rnd++) & 1], w, lane);
    sh = fmaxf(vv[0] / 127.0f, 1e-8f);
    float ish = 1.0f / sh;
    #pragma unroll
    for (int rt = 0; rt < 4; ++rt)
      #pragma unroll
      for (int rg = 0; rg < 4; ++rg)
        ah[(rt * 16 + lh * 4 + rg) * 272 + j] =
            (signed char)(int)clamp128(rintf(h[rt][rg] * ish));
    __syncthreads();
  }

  for (int t = 0; t < T_STEPS; ++t) {
    // ---- GEMM: M = ah(64x256,i8) @ BR(256x768,i8), exact int32 ----
    v4i acc[3][4];
    #pragma unroll
    for (int p = 0; p < 3; ++p)
      #pragma unroll
      for (int rt = 0; rt < 4; ++rt) acc[p][rt] = (v4i){0, 0, 0, 0};
    #pragma unroll
    for (int kc = 0; kc < 4; ++kc)
      #pragma unroll
      for (int rt = 0; rt < 4; ++rt) {
        v4i A = *(const v4i*)(ah + (rt * 16 + cl) * 272 + lh * 16 + kc * 64);
        acc[0][rt] = MFMA_I8(A, Bz[kc], acc[0][rt]);
        acc[1][rt] = MFMA_I8(A, Br[kc], acc[1][rt]);
        acc[2][rt] = MFMA_I8(A, Bn[kc], acc[2][rt]);
      }
    // Wx for this step: 3 coalesced dwordx4 per thread (frag-order layout)
    v4i wv[3];
    #pragma unroll
    for (int p = 0; p < 3; ++p)
      wv[p] = *(const v4i*)(wxq + ((size_t)(t * 3 + p) << 14) + tid * 16);

    // ---- R1: global max |M| ----
    int mm = 0;
    #pragma unroll
    for (int p = 0; p < 3; ++p)
      #pragma unroll
      for (int rt = 0; rt < 4; ++rt)
        #pragma unroll
        for (int rg = 0; rg < 4; ++rg) mm = max(mm, abs(acc[p][rt][rg]));
    mm = bredmax_i(mm, redi[(rnd++) & 1], w, lane);
    float maxMf = (float)mm;
    float s_Rh = fmaxf(sh * s_R * maxMf / 127.0f, 1e-8f);
    float fRh = (sh * s_R) / s_Rh;     // guard-safe quant factor

    // ---- stage 1: z_pre, r_pre, Rh_n+br_n (+ their maxes) ----
    float zp[4][4], rp[4][4], nb[4][4];
    float az = 0, ar = 0, an = 0;
    #pragma unroll
    for (int rt = 0; rt < 4; ++rt)
      #pragma unroll
      for (int rg = 0; rg < 4; ++rg) {
        float Rz = s_Rh * clamp128(rintf((float)acc[0][rt][rg] * fRh));
        float Rr = s_Rh * clamp128(rintf((float)acc[1][rt][rg] * fRh));
        float Rn = s_Rh * clamp128(rintf((float)acc[2][rt][rg] * fRh));
        float wz = s_wx * (float)((signed char)(wv[0][rt] >> (rg * 8)));
        float wr = s_wx * (float)((signed char)(wv[1][rt] >> (rg * 8)));
        float a1 = ((wz + bxz) + Rz) + brz;
        float a2 = ((wr + bxr) + Rr) + brr;
        float a3 = Rn + brn;
        zp[rt][rg] = a1; rp[rt][rg] = a2; nb[rt][rg] = a3;
        az = fmaxf(az, fabsf(a1));
        ar = fmaxf(ar, fabsf(a2));
        an = fmaxf(an, fabsf(a3));
      }
    float v3[3] = {az, ar, an};
    bredmax<3>(v3, redf[(rnd++) & 1], w, lane);                       // R2
    float s1 = fmaxf(v3[0] / 127.0f, 1e-8f), i1 = 1.0f / s1;
    float s2 = fmaxf(v3[1] / 127.0f, 1e-8f), i2 = 1.0f / s2;
    float s3 = fmaxf(v3[2] / 127.0f, 1e-8f), i3 = 1.0f / s3;

    // ---- stage 2: sigmoids + quantize nb ----
    float zs[4][4], rs[4][4];
    float mz = 0, mr = 0;
    #pragma unroll
    for (int rt = 0; rt < 4; ++rt)
      #pragma unroll
      for (int rg = 0; rg < 4; ++rg) {
        float zq = s1 * clamp128(rintf(zp[rt][rg] * i1));
        float rq = s2 * clamp128(rintf(rp[rt][rg] * i2));
        float zv = sigmoidf_(zq);
        float rv = sigmoidf_(rq);
        zs[rt][rg] = zv; rs[rt][rg] = rv;
        mz = fmaxf(mz, zv); mr = fmaxf(mr, rv);
        nb[rt][rg] = s3 * clamp128(rintf(nb[rt][rg] * i3));
      }
    float v2[2] = {mz, mr};
    bredmax<2>(v2, redf[(rnd++) & 1], w, lane);                       // R3
    float s4 = fmaxf(v2[0] / 127.0f, 1e-8f), i4 = 1.0f / s4;
    float s5 = fmaxf(v2[1] / 127.0f, 1e-8f), i5 = 1.0f / s5;

    // ---- stage 3: quantize z, r ; rRh = r*(Rh_n+br_n) ----
    float m6 = 0;
    #pragma unroll
    for (int rt = 0; rt < 4; ++rt)
      #pragma unroll
      for (int rg = 0; rg < 4; ++rg) {
        zs[rt][rg] = s4 * clamp128(rintf(zs[rt][rg] * i4));   // final z
        float rq2 = s5 * clamp128(rintf(rs[rt][rg] * i5));
        float rr_ = rq2 * nb[rt][rg];
        rs[rt][rg] = rr_;
        m6 = fmaxf(m6, fabsf(rr_));
      }
    float v1[1] = {m6};
    bredmax<1>(v1, redf[(rnd++) & 1], w, lane);                       // R4
    float s6 = fmaxf(v1[0] / 127.0f, 1e-8f), i6 = 1.0f / s6;

    // ---- stage 4: g_pre ----
    float m7 = 0;
    #pragma unroll
    for (int rt = 0; rt < 4; ++rt)
      #pragma unroll
      for (int rg = 0; rg < 4; ++rg) {
        float rrq = s6 * clamp128(rintf(rs[rt][rg] * i6));
        float wn = s_wx * (float)((signed char)(wv[2][rt] >> (rg * 8)));
        float gp = (wn + bxn) + rrq;
        rs[rt][rg] = gp;
        m7 = fmaxf(m7, fabsf(gp));
      }
    v1[0] = m7;
    bredmax<1>(v1, redf[(rnd++) & 1], w, lane);                       // R5
    float s7 = fmaxf(v1[0] / 127.0f, 1e-8f), i7 = 1.0f / s7;

    // ---- stage 5: g = tanh(g_pre_q) ----
    float m8 = 0;
    #pragma unroll
    for (int rt = 0; rt < 4; ++rt)
      #pragma unroll
      for (int rg = 0; rg < 4; ++rg) {
        float gpq = s7 * clamp128(rintf(rs[rt][rg] * i7));
        float gv = tanhf_(gpq);
        rs[rt][rg] = gv;
        m8 = fmaxf(m8, fabsf(gv));
      }
    v1[0] = m8;
    bredmax<1>(v1, redf[(rnd++) & 1], w, lane);                       // R6
    float s8 = fmaxf(v1[0] / 127.0f, 1e-8f), i8v = 1.0f / s8;

    // ---- stage 6: old = z*h, new = (1-z)*g ----
    float mo = 0, mn = 0;
    #pragma unroll
    for (int rt = 0; rt < 4; ++rt)
      #pragma unroll
      for (int rg = 0; rg < 4; ++rg) {
        float gq = s8 * clamp128(rintf(rs[rt][rg] * i8v));
        float zf = zs[rt][rg];
        float ov = zf * h[rt][rg];
        float nv = (1.0f - zf) * gq;
        zp[rt][rg] = ov; rp[rt][rg] = nv;
        mo = fmaxf(mo, fabsf(ov)); mn = fmaxf(mn, fabsf(nv));
      }
    v2[0] = mo; v2[1] = mn;
    bredmax<2>(v2, redf[(rnd++) & 1], w, lane);                       // R7
    float s9  = fmaxf(v2[0] / 127.0f, 1e-8f), i9  = 1.0f / s9;
    float s10 = fmaxf(v2[1] / 127.0f, 1e-8f), i10 = 1.0f / s10;

    // ---- stage 7: h_new ; write output ----
    float mh = 0;
    #pragma unroll
    for (int rt = 0; rt < 4; ++rt)
      #pragma unroll
      for (int rg = 0; rg < 4; ++rg) {
        float oq = s9  * clamp128(rintf(zp[rt][rg] * i9));
        float nq = s10 * clamp128(rintf(rp[rt][rg] * i10));
        float hn = oq + nq;
        h[rt][rg] = hn;
        mh = fmaxf(mh, fabsf(hn));
        out[t * 16384 + (rt * 16 + lh * 4 + rg) * 256 + j] = hn;
      }
    v1[0] = mh;
    bredmax<1>(v1, redf[(rnd++) & 1], w, lane);                       // R8
    sh = fmaxf(v1[0] / 127.0f, 1e-8f);
    float ish = 1.0f / sh;
    #pragma unroll
    for (int rt = 0; rt < 4; ++rt)
      #pragma unroll
      for (int rg = 0; rg < 4; ++rg)
        ah[(rt * 16 + lh * 4 + rg) * 272 + j] =
            (signed char)(int)clamp128(rintf(h[rt][rg] * ish));
    __syncthreads();   // ah ready for next step's GEMM
  }

  // h_last (second output chunk)
  #pragma unroll
  for (int rt = 0; rt < 4; ++rt)
    #pragma unroll
    for (int rg = 0; rg < 4; ++rg)
      out[OUT_MAIN_FLOATS + (rt * 16 + lh * 4 + rg) * 256 + j] = h[rt][rg];
}

// ============================================================================
extern "C" void kernel_launch(void* const* d_in, const int* in_sizes, int n_in,
                              void* d_out, int out_size, void* d_ws, size_t ws_size,
                              hipStream_t stream) {
  const float* x   = (const float*)d_in[0];   // (1024,64,256)
  const float* wih = (const float*)d_in[1];   // (768,256)
  const float* whh = (const float*)d_in[2];   // (768,256)
  const float* bih = (const float*)d_in[3];   // (768,)
  const float* bhh = (const float*)d_in[4];   // (768,)
  const float* h0  = (const float*)d_in[5];   // (64,256)
  float* out = (float*)d_out;

  unsigned* slots = (unsigned*)d_ws;                           // 256 B
  signed char* brf = (signed char*)d_ws + 256;                 // 196,608 B
  float* bq = (float*)((char*)d_ws + 256 + 196608);            // 6,144 B
  // Wxq int8 lives in the TAIL of d_out (write-ptr never catches read-ptr)
  signed char* wxq = (signed char*)d_out + WXQ_DOUT_OFF;

  hipMemsetAsync(d_ws, 0, 256, stream);

  k_absmax<<<dim3(1024), dim3(256), 0, stream>>>(x,   16777216 / 4, slots + 0);
  k_absmax<<<dim3(96),   dim3(256), 0, stream>>>(wih, 196608 / 4,   slots + 1);
  k_absmax<<<dim3(96),   dim3(256), 0, stream>>>(whh, 196608 / 4,   slots + 2);
  k_absmax<<<dim3(1),    dim3(256), 0, stream>>>(bih, 768 / 4,      slots + 3);
  k_absmax<<<dim3(1),    dim3(256), 0, stream>>>(bhh, 768 / 4,      slots + 4);

  k_brfrag<<<dim3(192), dim3(256), 0, stream>>>(whh, slots, brf);
  k_bias<<<dim3(1), dim3(768), 0, stream>>>(bih, bhh, slots, bq);

  dim3 g(12, 1024);
  k_wx_gemm<<<g, dim3(256), 0, stream>>>(x, wih, slots, wxq, 0);  // global max
  k_wx_gemm<<<g, dim3(256), 0, stream>>>(x, wih, slots, wxq, 1);  // write int8

  k_recur<<<dim3(1), dim3(1024), 0, stream>>>(wxq, brf, bq, slots, h0, out);
}

// Round 2
// 19399.690 us; speedup vs baseline: 1.6385x; 1.6385x over previous
//
#include <hip/hip_runtime.h>
#include <cstdint>
#include <cstddef>

// ============================================================================
// QuantGRU on MI355X — round 1
//
// Changes vs round 0 (which passed but spilled heavily in k_recur):
//  * Recurrence ROW-SPLIT across 4 workgroups (4 CUs). Batch rows are
//    independent; only the per-tensor fake-quant scales couple WGs, so each
//    of the 6 reduction rounds per step becomes a 4-WG global max exchange
//    (device-scope atomics + monotone counter barrier; grid=4 => co-resident).
//  * 8 reduction rounds -> 6: s4/s5 (sigmoid maxes) derived from SIGNED max
//    of z_pre/r_pre (sigmoid monotone), s8 (tanh max) derived from R5's
//    max|g_pre| (tanh monotone). Bit-identical to reducing post-activation.
//  * Per-thread register footprint ~100 (acc 12, temps ~32) => no spills.
//  * Prologue Wx GEMM now int8-MFMA (exact same integers as fp32 version).
// ============================================================================

typedef int   v4i __attribute__((ext_vector_type(4)));
typedef float v4f __attribute__((ext_vector_type(4)));

#define T_STEPS 1024
#define OUT_MAIN_FLOATS (1024*64*256)          // 16,777,216
#define WXQ_DOUT_OFF 16842752                  // out_bytes(67,174,400) - 50,331,648

__device__ __forceinline__ float clamp128(float x) {
  return fminf(fmaxf(x, -128.0f), 127.0f);
}
__device__ __forceinline__ int permj(int j) {           // haste row -> pt row
  return j < 256 ? j + 256 : (j < 512 ? j - 256 : j);
}
__device__ __forceinline__ float sigmoidf_(float x) {
  return __fdividef(1.0f, 1.0f + __expf(-x));
}
__device__ __forceinline__ float tanhf_(float x) {
  float e = __expf(-2.0f * fabsf(x));
  float t = __fdividef(1.0f - e, 1.0f + e);
  return copysignf(t, x);
}
__device__ __forceinline__ float wave_amax(float v) {
  #pragma unroll
  for (int m = 1; m <= 32; m <<= 1) v = fmaxf(v, __shfl_xor(v, m, 64));
  return v;
}
// monotone uint key for signed float max
__device__ __forceinline__ unsigned skey(float x) {
  unsigned u = __float_as_uint(x);
  return (u & 0x80000000u) ? ~u : (u | 0x80000000u);
}
__device__ __forceinline__ float sdec(unsigned k) {
  unsigned u = (k & 0x80000000u) ? (k ^ 0x80000000u) : ~k;
  return __uint_as_float(u);
}

#define MFMA_I8(a, b, c) __builtin_amdgcn_mfma_i32_16x16x64_i8(a, b, c, 0, 0, 0)

// ---------------- absmax over a float tensor (n4 = n/4) ----------------
__global__ void k_absmax(const float* __restrict__ p, int n4, unsigned* slot) {
  int i = blockIdx.x * blockDim.x + threadIdx.x;
  int stride = gridDim.x * blockDim.x;
  const v4f* p4 = (const v4f*)p;
  float m = 0.0f;
  for (; i < n4; i += stride) {
    v4f v = p4[i];
    m = fmaxf(m, fmaxf(fmaxf(fabsf(v[0]), fabsf(v[1])),
                       fmaxf(fabsf(v[2]), fabsf(v[3]))));
  }
  m = wave_amax(m);
  if ((threadIdx.x & 63) == 0) atomicMax(slot, __float_as_uint(m));
}

// ---------------- 768x256 weight -> int8 MFMA B-fragments ----------------
// byte addr = ((ct*4+kc)*64 + lane)*16 + b ; value B[k][n], n = ct*16+(lane&15),
// k = kc*64 + (lane>>4)*16 + b.  B[k][n] = src[permj(n)][k].
__global__ void k_frag(const float* __restrict__ src,
                       const unsigned* __restrict__ slots, int slot_idx,
                       signed char* __restrict__ dst) {
  int id = blockIdx.x * 256 + threadIdx.x;   // 0..49151
  float s = fmaxf(__uint_as_float(slots[slot_idx]) / 127.0f, 1e-8f);
  int bq   = id & 3;
  int lane = (id >> 2) & 63;
  int kc   = (id >> 8) & 3;
  int ct   = id >> 10;
  int n = ct * 16 + (lane & 15);
  int k = kc * 64 + (lane >> 4) * 16 + bq * 4;
  const float* p = src + permj(n) * 256 + k;
  int b0 = ((int)clamp128(rintf(p[0] / s))) & 255;
  int b1 = ((int)clamp128(rintf(p[1] / s))) & 255;
  int b2 = ((int)clamp128(rintf(p[2] / s))) & 255;
  int b3 = ((int)clamp128(rintf(p[3] / s))) & 255;
  ((int*)dst)[id] = b0 | (b1 << 8) | (b2 << 16) | (b3 << 24);
}

// ---------------- biases: reorder + fake-quant (dequantized fp32) ----------
__global__ void k_bias(const float* __restrict__ bih, const float* __restrict__ bhh,
                       const unsigned* __restrict__ slots, float* __restrict__ bqo) {
  int j = threadIdx.x;               // 0..767
  float s_bx = fmaxf(__uint_as_float(slots[3]) / 127.0f, 1e-8f);
  float s_br = fmaxf(__uint_as_float(slots[4]) / 127.0f, 1e-8f);
  int pr = permj(j);
  bqo[j]       = s_bx * clamp128(rintf(bih[pr] / s_bx));
  bqo[768 + j] = s_br * clamp128(rintf(bhh[pr] / s_br));
}

// ---------------- quantize x -> int8 (row-major, same ints as round 0) -----
__global__ void k_xq(const float* __restrict__ x, const unsigned* __restrict__ slots,
                     signed char* __restrict__ xq8, int n4) {
  int i = blockIdx.x * blockDim.x + threadIdx.x;
  if (i >= n4) return;
  float s_x = fmaxf(__uint_as_float(slots[0]) / 127.0f, 1e-8f);
  v4f v = ((const v4f*)x)[i];
  int b0 = ((int)clamp128(rintf(v[0] / s_x))) & 255;
  int b1 = ((int)clamp128(rintf(v[1] / s_x))) & 255;
  int b2 = ((int)clamp128(rintf(v[2] / s_x))) & 255;
  int b3 = ((int)clamp128(rintf(v[3] / s_x))) & 255;
  ((int*)xq8)[i] = b0 | (b1 << 8) | (b2 << 16) | (b3 << 24);
}

// ---------------- Wx GEMM, int8 MFMA (both passes) ----------------
// Per block t: C(64x768) = xq8[t] (64x256) @ Wfrag (256x768). Exact int32.
// mode 0: atomicMax global max|C|; mode 1: write int8 Wxq in k_recur4 order.
__global__ __launch_bounds__(1024) void k_wx_i8(
    const signed char* __restrict__ xq8, const signed char* __restrict__ wf,
    unsigned* __restrict__ slots, signed char* __restrict__ wxq, int mode) {
  const int t = blockIdx.x;
  const int tid = threadIdx.x, lane = tid & 63, w = tid >> 6;
  const int cl = lane & 15, lh = lane >> 4;

  v4i Bz[4], Br[4], Bn[4];
  #pragma unroll
  for (int kc = 0; kc < 4; ++kc) {
    Bz[kc] = *(const v4i*)(wf + (((w)*4      + kc) * 64 + lane) * 16);
    Br[kc] = *(const v4i*)(wf + (((w + 16)*4 + kc) * 64 + lane) * 16);
    Bn[kc] = *(const v4i*)(wf + (((w + 32)*4 + kc) * 64 + lane) * 16);
  }
  v4i acc[3][4];
  #pragma unroll
  for (int p = 0; p < 3; ++p)
    #pragma unroll
    for (int rt = 0; rt < 4; ++rt) acc[p][rt] = (v4i){0, 0, 0, 0};

  const signed char* xr = xq8 + t * 16384;
  #pragma unroll
  for (int kc = 0; kc < 4; ++kc)
    #pragma unroll
    for (int rt = 0; rt < 4; ++rt) {
      v4i A = *(const v4i*)(xr + (rt * 16 + cl) * 256 + kc * 64 + lh * 16);
      acc[0][rt] = MFMA_I8(A, Bz[kc], acc[0][rt]);
      acc[1][rt] = MFMA_I8(A, Br[kc], acc[1][rt]);
      acc[2][rt] = MFMA_I8(A, Bn[kc], acc[2][rt]);
    }

  if (mode == 0) {
    int mm = 0;
    #pragma unroll
    for (int p = 0; p < 3; ++p)
      #pragma unroll
      for (int rt = 0; rt < 4; ++rt)
        #pragma unroll
        for (int rg = 0; rg < 4; ++rg) mm = max(mm, abs(acc[p][rt][rg]));
    #pragma unroll
    for (int m = 1; m <= 32; m <<= 1) mm = max(mm, __shfl_xor(mm, m, 64));
    if (lane == 0) atomicMax((int*)(slots + 5), mm);
  } else {
    int islot = *(const int*)(slots + 5);
    float maxMf = (float)islot;
    float s_x = fmaxf(__uint_as_float(slots[0]) / 127.0f, 1e-8f);
    float s_W = fmaxf(__uint_as_float(slots[1]) / 127.0f, 1e-8f);
    float s_xW = s_x * s_W;
    float s_wx = fmaxf(s_xW * maxMf / 127.0f, 1e-8f);
    #pragma unroll
    for (int p = 0; p < 3; ++p)
      #pragma unroll
      for (int rt = 0; rt < 4; ++rt) {
        int dw = 0;
        #pragma unroll
        for (int rg = 0; rg < 4; ++rg) {
          float qf = clamp128(rintf((s_xW * (float)acc[p][rt][rg]) / s_wx));
          dw |= (((int)qf) & 255) << (rg * 8);
        }
        ((int*)wxq)[t * 12288 + p * 4096 + rt * 1024 + w * 64 + lh * 16 + cl] = dw;
      }
  }
}

// ---------------- cross-WG max round (4 workgroups) ----------------
// LDS combine (wave shfl + lane0 atomicMax) -> tid0 publishes to global ring
// slot, arrives on monotone counter, spins, combines 4 WGs, broadcasts via LDS.
template <int NCH>
__device__ __forceinline__ void ground(unsigned* keys, int gr,
    unsigned* lred /*[24]*/, unsigned* gcnt, unsigned* gpart,
    int wg, int tid, int lane) {
  const int bank = gr % 3;
  const int ring = gr & 7;
  #pragma unroll
  for (int c = 0; c < NCH; ++c) {
    unsigned v = keys[c];
    #pragma unroll
    for (int m = 1; m <= 32; m <<= 1)
      v = max(v, (unsigned)__shfl_xor((int)v, m, 64));
    keys[c] = v;
  }
  if (lane == 0) {
    #pragma unroll
    for (int c = 0; c < NCH; ++c) atomicMax(&lred[bank * 8 + c], keys[c]);
  }
  __syncthreads();
  if (tid == 0) {
    unsigned* myp = gpart + (ring * 4 + wg) * 8;
    #pragma unroll
    for (int c = 0; c < NCH; ++c)
      __hip_atomic_store(myp + c, lred[bank * 8 + c],
                         __ATOMIC_RELAXED, __HIP_MEMORY_SCOPE_AGENT);
    __hip_atomic_fetch_add(gcnt, 1u, __ATOMIC_RELEASE, __HIP_MEMORY_SCOPE_AGENT);
    unsigned tgt = 4u * (unsigned)gr + 4u;
    while (__hip_atomic_load(gcnt, __ATOMIC_ACQUIRE, __HIP_MEMORY_SCOPE_AGENT) < tgt) {}
    unsigned comb[NCH];
    #pragma unroll
    for (int c = 0; c < NCH; ++c) comb[c] = 0u;
    #pragma unroll
    for (int o = 0; o < 4; ++o) {
      unsigned* op = gpart + (ring * 4 + o) * 8;
      #pragma unroll
      for (int c = 0; c < NCH; ++c) {
        unsigned v = __hip_atomic_load(op + c, __ATOMIC_RELAXED,
                                       __HIP_MEMORY_SCOPE_AGENT);
        comb[c] = max(comb[c], v);
      }
    }
    #pragma unroll
    for (int c = 0; c < NCH; ++c) lred[bank * 8 + c] = comb[c];
    int nb = bank + 1; if (nb == 3) nb = 0;          // zero next bank (3-phase safe)
    #pragma unroll
    for (int c = 0; c < 8; ++c) lred[nb * 8 + c] = 0u;
  }
  __syncthreads();
  #pragma unroll
  for (int c = 0; c < NCH; ++c) keys[c] = lred[bank * 8 + c];
}

// ---------------- the recurrence: 4 workgroups, 16 batch rows each ---------
__global__ __launch_bounds__(1024) void k_recur4(
    const signed char* __restrict__ wxq, const signed char* __restrict__ brf,
    const float* __restrict__ bq, const unsigned* __restrict__ slots,
    const float* __restrict__ h0p, float* __restrict__ out,
    unsigned* __restrict__ gcnt, unsigned* __restrict__ gpart) {
  __shared__ signed char ah[16 * 272];     // int8 h rows (WG-local), pad stride
  __shared__ unsigned lred[24];            // 3 banks x 8 channels

  const int tid = threadIdx.x;
  const int lane = tid & 63;
  const int w = tid >> 6;                  // 16 waves: col tile {w, w+16, w+32}
  const int cl = lane & 15;
  const int lh = lane >> 4;
  const int wg = blockIdx.x;               // 0..3 -> batch rows 16*wg..+15
  const int j = w * 16 + cl;               // h column 0..255
  const int brow = wg * 16 + lh * 4;       // +rg = global batch row

  if (tid < 24) lred[tid] = 0u;

  float s_x = fmaxf(__uint_as_float(slots[0]) / 127.0f, 1e-8f);
  float s_W = fmaxf(__uint_as_float(slots[1]) / 127.0f, 1e-8f);
  float s_R = fmaxf(__uint_as_float(slots[2]) / 127.0f, 1e-8f);
  float maxM0 = (float)(*(const int*)(slots + 5));
  float s_wx = fmaxf(s_x * s_W * maxM0 / 127.0f, 1e-8f);

  float bxz = bq[j], bxr = bq[j + 256], bxn = bq[j + 512];
  float brz = bq[768 + j], brr = bq[1024 + j], brn = bq[1280 + j];

  v4i Bz[4], Br[4], Bn[4];                 // R fragments, resident (48 VGPR)
  #pragma unroll
  for (int kc = 0; kc < 4; ++kc) {
    Bz[kc] = *(const v4i*)(brf + (((w)*4      + kc) * 64 + lane) * 16);
    Br[kc] = *(const v4i*)(brf + (((w + 16)*4 + kc) * 64 + lane) * 16);
    Bn[kc] = *(const v4i*)(brf + (((w + 32)*4 + kc) * 64 + lane) * 16);
  }

  float h[4];
  #pragma unroll
  for (int rg = 0; rg < 4; ++rg) h[rg] = h0p[(brow + rg) * 256 + j];

  __syncthreads();                         // lred zero visible

  int gr = 0;
  float sh;
  {
    float m = fmaxf(fmaxf(fabsf(h[0]), fabsf(h[1])),
                    fmaxf(fabsf(h[2]), fabsf(h[3])));
    unsigned kk[1] = {__float_as_uint(m)};
    ground<1>(kk, gr, lred, gcnt, gpart, wg, tid, lane); ++gr;
    sh = fmaxf(__uint_as_float(kk[0]) / 127.0f, 1e-8f);
    float ish = 1.0f / sh;
    #pragma unroll
    for (int rg = 0; rg < 4; ++rg)
      ah[(lh * 4 + rg) * 272 + j] =
          (signed char)(int)clamp128(rintf(h[rg] * ish));
    __syncthreads();
  }

  for (int t = 0; t < T_STEPS; ++t) {
    // Wx bytes for this step (coalesced dwords)
    const signed char* wb = wxq + (size_t)t * 49152 + (wg << 12) + (tid << 2);
    int wvz = *(const int*)(wb);
    int wvr = *(const int*)(wb + 16384);
    int wvn = *(const int*)(wb + 32768);

    // ---- GEMM: 16x768 = ah(16x256,i8) @ R(256x768,i8), exact ----
    v4i az4 = {0,0,0,0}, ar4 = {0,0,0,0}, an4 = {0,0,0,0};
    #pragma unroll
    for (int kc = 0; kc < 4; ++kc) {
      v4i A = *(const v4i*)(ah + cl * 272 + kc * 64 + lh * 16);
      az4 = MFMA_I8(A, Bz[kc], az4);
      ar4 = MFMA_I8(A, Br[kc], ar4);
      an4 = MFMA_I8(A, Bn[kc], an4);
    }

    // ---- R1: global max|acc| ----
    int mm = 0;
    #pragma unroll
    for (int rg = 0; rg < 4; ++rg)
      mm = max(mm, max(abs(az4[rg]), max(abs(ar4[rg]), abs(an4[rg]))));
    unsigned kk[5];
    kk[0] = (unsigned)mm;
    ground<1>(kk, gr, lred, gcnt, gpart, wg, tid, lane); ++gr;
    float maxMf = (float)(int)kk[0];
    float s_Rh = fmaxf(sh * s_R * maxMf / 127.0f, 1e-8f);
    float fRh = (sh * s_R) / s_Rh;

    // ---- stage B: z_pre, r_pre, Rh_n+br_n + abs/signed maxes ----
    float zp[4], rp[4], nb[4];
    float az = 0.0f, ar = 0.0f, an = 0.0f;
    float mzs = -3.402823466e38f, mrs = -3.402823466e38f;
    #pragma unroll
    for (int rg = 0; rg < 4; ++rg) {
      float Rz = s_Rh * clamp128(rintf((float)az4[rg] * fRh));
      float Rr = s_Rh * clamp128(rintf((float)ar4[rg] * fRh));
      float Rn = s_Rh * clamp128(rintf((float)an4[rg] * fRh));
      float wz = s_wx * (float)((signed char)(wvz >> (rg * 8)));
      float wr = s_wx * (float)((signed char)(wvr >> (rg * 8)));
      float a1 = ((wz + bxz) + Rz) + brz;
      float a2 = ((wr + bxr) + Rr) + brr;
      float a3 = Rn + brn;
      zp[rg] = a1; rp[rg] = a2; nb[rg] = a3;
      az = fmaxf(az, fabsf(a1)); ar = fmaxf(ar, fabsf(a2));
      an = fmaxf(an, fabsf(a3));
      mzs = fmaxf(mzs, a1); mrs = fmaxf(mrs, a2);
    }
    kk[0] = __float_as_uint(az); kk[1] = __float_as_uint(ar);
    kk[2] = __float_as_uint(an); kk[3] = skey(mzs); kk[4] = skey(mrs);
    ground<5>(kk, gr, lred, gcnt, gpart, wg, tid, lane); ++gr;
    float s1 = fmaxf(__uint_as_float(kk[0]) / 127.0f, 1e-8f), i1 = 1.0f / s1;
    float s2 = fmaxf(__uint_as_float(kk[1]) / 127.0f, 1e-8f), i2 = 1.0f / s2;
    float s3 = fmaxf(__uint_as_float(kk[2]) / 127.0f, 1e-8f), i3 = 1.0f / s3;
    // sigmoid is monotone: its max is sigmoid of the quantized signed max
    float zq_max = s1 * clamp128(rintf(sdec(kk[3]) * i1));
    float rq_max = s2 * clamp128(rintf(sdec(kk[4]) * i2));
    float s4 = fmaxf(sigmoidf_(zq_max) / 127.0f, 1e-8f), i4 = 1.0f / s4;
    float s5 = fmaxf(sigmoidf_(rq_max) / 127.0f, 1e-8f), i5 = 1.0f / s5;

    // ---- stage C: z final, rRh ----
    float zf[4], rr_[4];
    float m6 = 0.0f;
    #pragma unroll
    for (int rg = 0; rg < 4; ++rg) {
      float zq = s1 * clamp128(rintf(zp[rg] * i1));
      float rq = s2 * clamp128(rintf(rp[rg] * i2));
      float zv = sigmoidf_(zq);
      float rv = sigmoidf_(rq);
      zf[rg] = s4 * clamp128(rintf(zv * i4));
      float rq2 = s5 * clamp128(rintf(rv * i5));
      float nbq = s3 * clamp128(rintf(nb[rg] * i3));
      float rr = rq2 * nbq;
      rr_[rg] = rr;
      m6 = fmaxf(m6, fabsf(rr));
    }
    kk[0] = __float_as_uint(m6);
    ground<1>(kk, gr, lred, gcnt, gpart, wg, tid, lane); ++gr;
    float s6 = fmaxf(__uint_as_float(kk[0]) / 127.0f, 1e-8f), i6 = 1.0f / s6;

    // ---- stage D: g_pre ----
    float gp[4];
    float m7 = 0.0f;
    #pragma unroll
    for (int rg = 0; rg < 4; ++rg) {
      float rrq = s6 * clamp128(rintf(rr_[rg] * i6));
      float wn = s_wx * (float)((signed char)(wvn >> (rg * 8)));
      float g = (wn + bxn) + rrq;
      gp[rg] = g;
      m7 = fmaxf(m7, fabsf(g));
    }
    kk[0] = __float_as_uint(m7);
    ground<1>(kk, gr, lred, gcnt, gpart, wg, tid, lane); ++gr;
    float m7g = __uint_as_float(kk[0]);
    float s7 = fmaxf(m7g / 127.0f, 1e-8f), i7 = 1.0f / s7;
    // tanh monotone: max|tanh| from quantized max|g_pre|
    float gq_max = s7 * clamp128(rintf(m7g * i7));
    float s8 = fmaxf(tanhf_(gq_max) / 127.0f, 1e-8f), i8v = 1.0f / s8;

    // ---- stage E: g, old/new contribs ----
    float ov[4], nv[4];
    float mo = 0.0f, mn = 0.0f;
    #pragma unroll
    for (int rg = 0; rg < 4; ++rg) {
      float gpq = s7 * clamp128(rintf(gp[rg] * i7));
      float gv = tanhf_(gpq);
      float gq = s8 * clamp128(rintf(gv * i8v));
      float o = zf[rg] * h[rg];
      float n = (1.0f - zf[rg]) * gq;
      ov[rg] = o; nv[rg] = n;
      mo = fmaxf(mo, fabsf(o)); mn = fmaxf(mn, fabsf(n));
    }
    kk[0] = __float_as_uint(mo); kk[1] = __float_as_uint(mn);
    ground<2>(kk, gr, lred, gcnt, gpart, wg, tid, lane); ++gr;
    float s9  = fmaxf(__uint_as_float(kk[0]) / 127.0f, 1e-8f), i9  = 1.0f / s9;
    float s10 = fmaxf(__uint_as_float(kk[1]) / 127.0f, 1e-8f), i10 = 1.0f / s10;

    // ---- stage F: h_new, write output ----
    float mh = 0.0f;
    #pragma unroll
    for (int rg = 0; rg < 4; ++rg) {
      float oq = s9  * clamp128(rintf(ov[rg] * i9));
      float nq = s10 * clamp128(rintf(nv[rg] * i10));
      float hn = oq + nq;
      h[rg] = hn;
      mh = fmaxf(mh, fabsf(hn));
      out[t * 16384 + (brow + rg) * 256 + j] = hn;
    }
    kk[0] = __float_as_uint(mh);
    ground<1>(kk, gr, lred, gcnt, gpart, wg, tid, lane); ++gr;
    sh = fmaxf(__uint_as_float(kk[0]) / 127.0f, 1e-8f);
    float ish = 1.0f / sh;
    #pragma unroll
    for (int rg = 0; rg < 4; ++rg)
      ah[(lh * 4 + rg) * 272 + j] =
          (signed char)(int)clamp128(rintf(h[rg] * ish));
    __syncthreads();                       // ah ready for next step (block-local)
  }

  // h_last
  #pragma unroll
  for (int rg = 0; rg < 4; ++rg)
    out[OUT_MAIN_FLOATS + (brow + rg) * 256 + j] = h[rg];
}

// ============================================================================
extern "C" void kernel_launch(void* const* d_in, const int* in_sizes, int n_in,
                              void* d_out, int out_size, void* d_ws, size_t ws_size,
                              hipStream_t stream) {
  const float* x   = (const float*)d_in[0];   // (1024,64,256)
  const float* wih = (const float*)d_in[1];   // (768,256)
  const float* whh = (const float*)d_in[2];   // (768,256)
  const float* bih = (const float*)d_in[3];   // (768,)
  const float* bhh = (const float*)d_in[4];   // (768,)
  const float* h0  = (const float*)d_in[5];   // (64,256)
  float* out = (float*)d_out;

  // d_ws layout: [0..255] absmax slots, [256] barrier counter,
  // [512..1535] partial-max ring (8 rings x 4 wg x 8 ch), [4096..] bq,
  // [10240..] shared fragment buffer F (used first for W, then for R).
  unsigned* slots = (unsigned*)d_ws;
  unsigned* gcnt  = (unsigned*)((char*)d_ws + 256);
  unsigned* gpart = (unsigned*)((char*)d_ws + 512);
  float* bq       = (float*)((char*)d_ws + 4096);
  signed char* F  = (signed char*)d_ws + 10240;          // 196,608 B

  // d_out tail: Wxq int8 (write/read frontier never crosses, see round 0)
  signed char* wxq = (signed char*)d_out + WXQ_DOUT_OFF;
  // d_out head (dead once k_wx_i8 finishes): xq8 int8 staging
  signed char* xq8 = (signed char*)d_out;

  hipMemsetAsync(d_ws, 0, 4096, stream);

  k_absmax<<<dim3(1024), dim3(256), 0, stream>>>(x,   16777216 / 4, slots + 0);
  k_absmax<<<dim3(96),   dim3(256), 0, stream>>>(wih, 196608 / 4,   slots + 1);
  k_absmax<<<dim3(96),   dim3(256), 0, stream>>>(whh, 196608 / 4,   slots + 2);
  k_absmax<<<dim3(1),    dim3(256), 0, stream>>>(bih, 768 / 4,      slots + 3);
  k_absmax<<<dim3(1),    dim3(256), 0, stream>>>(bhh, 768 / 4,      slots + 4);

  k_frag<<<dim3(192), dim3(256), 0, stream>>>(wih, slots, 1, F);   // W frags
  k_bias<<<dim3(1), dim3(768), 0, stream>>>(bih, bhh, slots, bq);
  k_xq<<<dim3(16384), dim3(256), 0, stream>>>(x, slots, xq8, 4194304);

  k_wx_i8<<<dim3(1024), dim3(1024), 0, stream>>>(xq8, F, slots, wxq, 0);
  k_wx_i8<<<dim3(1024), dim3(1024), 0, stream>>>(xq8, F, slots, wxq, 1);

  k_frag<<<dim3(192), dim3(256), 0, stream>>>(whh, slots, 2, F);   // R frags

  k_recur4<<<dim3(4), dim3(1024), 0, stream>>>(wxq, F, bq, slots, h0, out,
                                               gcnt, gpart);
}

// Round 3
// 15988.301 us; speedup vs baseline: 1.9881x; 1.2134x over previous
//
#include <hip/hip_runtime.h>
#include <cstdint>
#include <cstddef>

// ============================================================================
// QuantGRU on MI355X — round 2
//
// vs round 1 (19.4 ms, exchange-round-bound at ~2.8 us/round):
//  * Cross-WG exchange: self-tagged {tag,value} 8B slots, one relaxed agent
//    dwordx2 store per channel (fire-and-forget), dedicated poller threads
//    spin on relaxed loads (no buffer_inv) and ds_atomic_max into LDS.
//    Parity double-buffer + monotone tags => no ABA / overwrite hazard.
//    ~1 L3 round-trip per round instead of ~3 serialized ones.
//  * All hot-loop clamp128 removed — proved bit-exact no-ops (scales are
//    max/127 of the exact tensor being quantized, incl. 1e-8 floor case).
//    Everything else in byte-identical op order (absmax margin is thin).
// ============================================================================

typedef int   v4i __attribute__((ext_vector_type(4)));
typedef float v4f __attribute__((ext_vector_type(4)));

#define T_STEPS 1024
#define OUT_MAIN_FLOATS (1024*64*256)          // 16,777,216
#define WXQ_DOUT_OFF 16842752                  // out_bytes(67,174,400) - 50,331,648

__device__ __forceinline__ float clamp128(float x) {
  return fminf(fmaxf(x, -128.0f), 127.0f);
}
__device__ __forceinline__ int permj(int j) {           // haste row -> pt row
  return j < 256 ? j + 256 : (j < 512 ? j - 256 : j);
}
__device__ __forceinline__ float sigmoidf_(float x) {
  return __fdividef(1.0f, 1.0f + __expf(-x));
}
__device__ __forceinline__ float tanhf_(float x) {
  float e = __expf(-2.0f * fabsf(x));
  float t = __fdividef(1.0f - e, 1.0f + e);
  return copysignf(t, x);
}
// monotone uint key for signed float max
__device__ __forceinline__ unsigned skey(float x) {
  unsigned u = __float_as_uint(x);
  return (u & 0x80000000u) ? ~u : (u | 0x80000000u);
}
__device__ __forceinline__ float sdec(unsigned k) {
  unsigned u = (k & 0x80000000u) ? (k ^ 0x80000000u) : ~k;
  return __uint_as_float(u);
}
__device__ __forceinline__ float wave_amax(float v) {
  #pragma unroll
  for (int m = 1; m <= 32; m <<= 1) v = fmaxf(v, __shfl_xor(v, m, 64));
  return v;
}

#define MFMA_I8(a, b, c) __builtin_amdgcn_mfma_i32_16x16x64_i8(a, b, c, 0, 0, 0)

// ---------------- absmax over a float tensor (n4 = n/4) ----------------
__global__ void k_absmax(const float* __restrict__ p, int n4, unsigned* slot) {
  int i = blockIdx.x * blockDim.x + threadIdx.x;
  int stride = gridDim.x * blockDim.x;
  const v4f* p4 = (const v4f*)p;
  float m = 0.0f;
  for (; i < n4; i += stride) {
    v4f v = p4[i];
    m = fmaxf(m, fmaxf(fmaxf(fabsf(v[0]), fabsf(v[1])),
                       fmaxf(fabsf(v[2]), fabsf(v[3]))));
  }
  m = wave_amax(m);
  if ((threadIdx.x & 63) == 0) atomicMax(slot, __float_as_uint(m));
}

// ---------------- 768x256 weight -> int8 MFMA B-fragments ----------------
__global__ void k_frag(const float* __restrict__ src,
                       const unsigned* __restrict__ slots, int slot_idx,
                       signed char* __restrict__ dst) {
  int id = blockIdx.x * 256 + threadIdx.x;   // 0..49151
  float s = fmaxf(__uint_as_float(slots[slot_idx]) / 127.0f, 1e-8f);
  int bq   = id & 3;
  int lane = (id >> 2) & 63;
  int kc   = (id >> 8) & 3;
  int ct   = id >> 10;
  int n = ct * 16 + (lane & 15);
  int k = kc * 64 + (lane >> 4) * 16 + bq * 4;
  const float* p = src + permj(n) * 256 + k;
  int b0 = ((int)clamp128(rintf(p[0] / s))) & 255;
  int b1 = ((int)clamp128(rintf(p[1] / s))) & 255;
  int b2 = ((int)clamp128(rintf(p[2] / s))) & 255;
  int b3 = ((int)clamp128(rintf(p[3] / s))) & 255;
  ((int*)dst)[id] = b0 | (b1 << 8) | (b2 << 16) | (b3 << 24);
}

// ---------------- biases: reorder + fake-quant (dequantized fp32) ----------
__global__ void k_bias(const float* __restrict__ bih, const float* __restrict__ bhh,
                       const unsigned* __restrict__ slots, float* __restrict__ bqo) {
  int j = threadIdx.x;               // 0..767
  float s_bx = fmaxf(__uint_as_float(slots[3]) / 127.0f, 1e-8f);
  float s_br = fmaxf(__uint_as_float(slots[4]) / 127.0f, 1e-8f);
  int pr = permj(j);
  bqo[j]       = s_bx * clamp128(rintf(bih[pr] / s_bx));
  bqo[768 + j] = s_br * clamp128(rintf(bhh[pr] / s_br));
}

// ---------------- quantize x -> int8 ----------------
__global__ void k_xq(const float* __restrict__ x, const unsigned* __restrict__ slots,
                     signed char* __restrict__ xq8, int n4) {
  int i = blockIdx.x * blockDim.x + threadIdx.x;
  if (i >= n4) return;
  float s_x = fmaxf(__uint_as_float(slots[0]) / 127.0f, 1e-8f);
  v4f v = ((const v4f*)x)[i];
  int b0 = ((int)clamp128(rintf(v[0] / s_x))) & 255;
  int b1 = ((int)clamp128(rintf(v[1] / s_x))) & 255;
  int b2 = ((int)clamp128(rintf(v[2] / s_x))) & 255;
  int b3 = ((int)clamp128(rintf(v[3] / s_x))) & 255;
  ((int*)xq8)[i] = b0 | (b1 << 8) | (b2 << 16) | (b3 << 24);
}

// ---------------- Wx GEMM, int8 MFMA (both passes) ----------------
__global__ __launch_bounds__(1024) void k_wx_i8(
    const signed char* __restrict__ xq8, const signed char* __restrict__ wf,
    unsigned* __restrict__ slots, signed char* __restrict__ wxq, int mode) {
  const int t = blockIdx.x;
  const int tid = threadIdx.x, lane = tid & 63, w = tid >> 6;
  const int cl = lane & 15, lh = lane >> 4;

  v4i Bz[4], Br[4], Bn[4];
  #pragma unroll
  for (int kc = 0; kc < 4; ++kc) {
    Bz[kc] = *(const v4i*)(wf + (((w)*4      + kc) * 64 + lane) * 16);
    Br[kc] = *(const v4i*)(wf + (((w + 16)*4 + kc) * 64 + lane) * 16);
    Bn[kc] = *(const v4i*)(wf + (((w + 32)*4 + kc) * 64 + lane) * 16);
  }
  v4i acc[3][4];
  #pragma unroll
  for (int p = 0; p < 3; ++p)
    #pragma unroll
    for (int rt = 0; rt < 4; ++rt) acc[p][rt] = (v4i){0, 0, 0, 0};

  const signed char* xr = xq8 + t * 16384;
  #pragma unroll
  for (int kc = 0; kc < 4; ++kc)
    #pragma unroll
    for (int rt = 0; rt < 4; ++rt) {
      v4i A = *(const v4i*)(xr + (rt * 16 + cl) * 256 + kc * 64 + lh * 16);
      acc[0][rt] = MFMA_I8(A, Bz[kc], acc[0][rt]);
      acc[1][rt] = MFMA_I8(A, Br[kc], acc[1][rt]);
      acc[2][rt] = MFMA_I8(A, Bn[kc], acc[2][rt]);
    }

  if (mode == 0) {
    int mm = 0;
    #pragma unroll
    for (int p = 0; p < 3; ++p)
      #pragma unroll
      for (int rt = 0; rt < 4; ++rt)
        #pragma unroll
        for (int rg = 0; rg < 4; ++rg) mm = max(mm, abs(acc[p][rt][rg]));
    #pragma unroll
    for (int m = 1; m <= 32; m <<= 1) mm = max(mm, __shfl_xor(mm, m, 64));
    if (lane == 0) atomicMax((int*)(slots + 5), mm);
  } else {
    int islot = *(const int*)(slots + 5);
    float maxMf = (float)islot;
    float s_x = fmaxf(__uint_as_float(slots[0]) / 127.0f, 1e-8f);
    float s_W = fmaxf(__uint_as_float(slots[1]) / 127.0f, 1e-8f);
    float s_xW = s_x * s_W;
    float s_wx = fmaxf(s_xW * maxMf / 127.0f, 1e-8f);
    #pragma unroll
    for (int p = 0; p < 3; ++p)
      #pragma unroll
      for (int rt = 0; rt < 4; ++rt) {
        int dw = 0;
        #pragma unroll
        for (int rg = 0; rg < 4; ++rg) {
          float qf = clamp128(rintf((s_xW * (float)acc[p][rt][rg]) / s_wx));
          dw |= (((int)qf) & 255) << (rg * 8);
        }
        ((int*)wxq)[t * 12288 + p * 4096 + rt * 1024 + w * 64 + lh * 16 + cl] = dw;
      }
  }
}

// ---------------- cross-WG max exchange, self-tagged slot protocol --------
// Slot = aligned 8B {tag:hi32, value:lo32}; one per (parity, wg, channel).
// Writers (wave0 lanes 0..NCH-1): single relaxed-agent dwordx2 store.
// Pollers (wave1, one per remote-wg x channel): spin relaxed load until
// hi32==tag, then ds_atomic_max value into the LDS result set.
// Parity double-buffer + monotone tags: a WG can only overwrite a parity
// slot two rounds later, which requires all peers published round r+1,
// which is ordered after they consumed round r (second barrier).  No ABA.
template <int NCH>
__device__ __forceinline__ void xchg(unsigned* keys, unsigned tag,
    unsigned (*lred)[8], unsigned long long* gslot, int wg, int tid, int lane) {
  const int rset = tag % 3;
  #pragma unroll
  for (int c = 0; c < NCH; ++c) {
    unsigned v = keys[c];
    #pragma unroll
    for (int m = 1; m <= 32; m <<= 1)
      v = max(v, (unsigned)__shfl_xor((int)v, m, 64));
    keys[c] = v;
  }
  if (lane == 0) {
    #pragma unroll
    for (int c = 0; c < NCH; ++c) atomicMax(&lred[rset][c], keys[c]);
  }
  __syncthreads();
  const int par = tag & 1;
  if (tid < NCH) {
    unsigned long long v =
        ((unsigned long long)tag << 32) | (unsigned long long)lred[rset][tid];
    __hip_atomic_store(&gslot[(par * 4 + wg) * 8 + tid], v,
                       __ATOMIC_RELAXED, __HIP_MEMORY_SCOPE_AGENT);
  } else if (tid == 32) {
    int ns = rset + 1; if (ns == 3) ns = 0;       // pre-zero next ring set
    #pragma unroll
    for (int c = 0; c < 8; ++c) lred[ns][c] = 0u;
  } else if (tid >= 64 && tid < 64 + 3 * NCH) {
    int idx = tid - 64;
    int owi = idx / NCH;
    int c = idx - owi * NCH;
    int ow = owi + (owi >= wg ? 1 : 0);
    unsigned long long* p = &gslot[(par * 4 + ow) * 8 + c];
    unsigned long long v;
    do {
      v = __hip_atomic_load(p, __ATOMIC_RELAXED, __HIP_MEMORY_SCOPE_AGENT);
    } while ((unsigned)(v >> 32) != tag);
    atomicMax(&lred[rset][c], (unsigned)v);
  }
  __syncthreads();
  #pragma unroll
  for (int c = 0; c < NCH; ++c) keys[c] = lred[rset][c];
}

// ---------------- the recurrence: 4 workgroups, 16 batch rows each ---------
__global__ __launch_bounds__(1024) void k_recur4b(
    const signed char* __restrict__ wxq, const signed char* __restrict__ brf,
    const float* __restrict__ bq, const unsigned* __restrict__ slots,
    const float* __restrict__ h0p, float* __restrict__ out,
    unsigned long long* __restrict__ gslot) {
  __shared__ signed char ah[16 * 272];     // int8 h rows (WG-local), pad stride
  __shared__ unsigned lred[3][8];          // 3-set ring x 8 channels

  const int tid = threadIdx.x;
  const int lane = tid & 63;
  const int w = tid >> 6;                  // 16 waves: col tiles {w, w+16, w+32}
  const int cl = lane & 15;
  const int lh = lane >> 4;
  const int wg = blockIdx.x;               // 0..3 -> batch rows 16*wg..+15
  const int j = w * 16 + cl;               // h column 0..255
  const int brow = wg * 16 + lh * 4;       // +rg = global batch row

  if (tid < 24) ((unsigned*)lred)[tid] = 0u;

  float s_x = fmaxf(__uint_as_float(slots[0]) / 127.0f, 1e-8f);
  float s_W = fmaxf(__uint_as_float(slots[1]) / 127.0f, 1e-8f);
  float s_R = fmaxf(__uint_as_float(slots[2]) / 127.0f, 1e-8f);
  float maxM0 = (float)(*(const int*)(slots + 5));
  float s_wx = fmaxf(s_x * s_W * maxM0 / 127.0f, 1e-8f);

  float bxz = bq[j], bxr = bq[j + 256], bxn = bq[j + 512];
  float brz = bq[768 + j], brr = bq[1024 + j], brn = bq[1280 + j];

  v4i Bz[4], Br[4], Bn[4];                 // R fragments, resident
  #pragma unroll
  for (int kc = 0; kc < 4; ++kc) {
    Bz[kc] = *(const v4i*)(brf + (((w)*4      + kc) * 64 + lane) * 16);
    Br[kc] = *(const v4i*)(brf + (((w + 16)*4 + kc) * 64 + lane) * 16);
    Bn[kc] = *(const v4i*)(brf + (((w + 32)*4 + kc) * 64 + lane) * 16);
  }

  float h[4];
  #pragma unroll
  for (int rg = 0; rg < 4; ++rg) h[rg] = h0p[(brow + rg) * 256 + j];

  __syncthreads();                         // lred zero visible

  unsigned tag = 1;
  float sh;
  {
    float m = fmaxf(fmaxf(fabsf(h[0]), fabsf(h[1])),
                    fmaxf(fabsf(h[2]), fabsf(h[3])));
    unsigned kk[1] = {__float_as_uint(m)};
    xchg<1>(kk, tag++, lred, gslot, wg, tid, lane);
    sh = fmaxf(__uint_as_float(kk[0]) / 127.0f, 1e-8f);
    float ish = 1.0f / sh;
    #pragma unroll
    for (int rg = 0; rg < 4; ++rg)
      ah[(lh * 4 + rg) * 272 + j] = (signed char)(int)rintf(h[rg] * ish);
    __syncthreads();
  }

  for (int t = 0; t < T_STEPS; ++t) {
    // Wx bytes for this step (coalesced dwords)
    const signed char* wb = wxq + (size_t)t * 49152 + (wg << 12) + (tid << 2);
    int wvz = *(const int*)(wb);
    int wvr = *(const int*)(wb + 16384);
    int wvn = *(const int*)(wb + 32768);

    // ---- GEMM: 16x768 = ah(16x256,i8) @ R(256x768,i8), exact ----
    v4i az4 = {0,0,0,0}, ar4 = {0,0,0,0}, an4 = {0,0,0,0};
    #pragma unroll
    for (int kc = 0; kc < 4; ++kc) {
      v4i A = *(const v4i*)(ah + cl * 272 + kc * 64 + lh * 16);
      az4 = MFMA_I8(A, Bz[kc], az4);
      ar4 = MFMA_I8(A, Br[kc], ar4);
      an4 = MFMA_I8(A, Bn[kc], an4);
    }

    // ---- R1: global max|acc| ----
    int mm = 0;
    #pragma unroll
    for (int rg = 0; rg < 4; ++rg)
      mm = max(mm, max(abs(az4[rg]), max(abs(ar4[rg]), abs(an4[rg]))));
    unsigned kk[5];
    kk[0] = (unsigned)mm;
    xchg<1>(kk, tag++, lred, gslot, wg, tid, lane);
    float maxMf = (float)(int)kk[0];
    float s_Rh = fmaxf(sh * s_R * maxMf / 127.0f, 1e-8f);
    float fRh = (sh * s_R) / s_Rh;

    // ---- stage B: z_pre, r_pre, Rh_n+br_n + abs/signed maxes ----
    float zp[4], rp[4], nb[4];
    float az = 0.0f, ar = 0.0f, an = 0.0f;
    float mzs = -3.402823466e38f, mrs = -3.402823466e38f;
    #pragma unroll
    for (int rg = 0; rg < 4; ++rg) {
      float Rz = s_Rh * rintf((float)az4[rg] * fRh);
      float Rr = s_Rh * rintf((float)ar4[rg] * fRh);
      float Rn = s_Rh * rintf((float)an4[rg] * fRh);
      float wz = s_wx * (float)((signed char)(wvz >> (rg * 8)));
      float wr = s_wx * (float)((signed char)(wvr >> (rg * 8)));
      float a1 = ((wz + bxz) + Rz) + brz;
      float a2 = ((wr + bxr) + Rr) + brr;
      float a3 = Rn + brn;
      zp[rg] = a1; rp[rg] = a2; nb[rg] = a3;
      az = fmaxf(az, fabsf(a1)); ar = fmaxf(ar, fabsf(a2));
      an = fmaxf(an, fabsf(a3));
      mzs = fmaxf(mzs, a1); mrs = fmaxf(mrs, a2);
    }
    kk[0] = __float_as_uint(az); kk[1] = __float_as_uint(ar);
    kk[2] = __float_as_uint(an); kk[3] = skey(mzs); kk[4] = skey(mrs);
    xchg<5>(kk, tag++, lred, gslot, wg, tid, lane);
    float s1 = fmaxf(__uint_as_float(kk[0]) / 127.0f, 1e-8f), i1 = 1.0f / s1;
    float s2 = fmaxf(__uint_as_float(kk[1]) / 127.0f, 1e-8f), i2 = 1.0f / s2;
    float s3 = fmaxf(__uint_as_float(kk[2]) / 127.0f, 1e-8f), i3 = 1.0f / s3;
    float zq_max = s1 * rintf(sdec(kk[3]) * i1);
    float rq_max = s2 * rintf(sdec(kk[4]) * i2);
    float s4 = fmaxf(sigmoidf_(zq_max) / 127.0f, 1e-8f), i4 = 1.0f / s4;
    float s5 = fmaxf(sigmoidf_(rq_max) / 127.0f, 1e-8f), i5 = 1.0f / s5;

    // ---- stage C: z final, rRh ----
    float zf[4], rr_[4];
    float m6 = 0.0f;
    #pragma unroll
    for (int rg = 0; rg < 4; ++rg) {
      float zq = s1 * rintf(zp[rg] * i1);
      float rq = s2 * rintf(rp[rg] * i2);
      float zv = sigmoidf_(zq);
      float rv = sigmoidf_(rq);
      zf[rg] = s4 * rintf(zv * i4);
      float rq2 = s5 * rintf(rv * i5);
      float nbq = s3 * rintf(nb[rg] * i3);
      float rr = rq2 * nbq;
      rr_[rg] = rr;
      m6 = fmaxf(m6, fabsf(rr));
    }
    kk[0] = __float_as_uint(m6);
    xchg<1>(kk, tag++, lred, gslot, wg, tid, lane);
    float s6 = fmaxf(__uint_as_float(kk[0]) / 127.0f, 1e-8f), i6 = 1.0f / s6;

    // ---- stage D: g_pre ----
    float gp[4];
    float m7 = 0.0f;
    #pragma unroll
    for (int rg = 0; rg < 4; ++rg) {
      float rrq = s6 * rintf(rr_[rg] * i6);
      float wn = s_wx * (float)((signed char)(wvn >> (rg * 8)));
      float g = (wn + bxn) + rrq;
      gp[rg] = g;
      m7 = fmaxf(m7, fabsf(g));
    }
    kk[0] = __float_as_uint(m7);
    xchg<1>(kk, tag++, lred, gslot, wg, tid, lane);
    float m7g = __uint_as_float(kk[0]);
    float s7 = fmaxf(m7g / 127.0f, 1e-8f), i7 = 1.0f / s7;
    float gq_max = s7 * rintf(m7g * i7);
    float s8 = fmaxf(tanhf_(gq_max) / 127.0f, 1e-8f), i8v = 1.0f / s8;

    // ---- stage E: g, old/new contribs ----
    float ov[4], nv[4];
    float mo = 0.0f, mn = 0.0f;
    #pragma unroll
    for (int rg = 0; rg < 4; ++rg) {
      float gpq = s7 * rintf(gp[rg] * i7);
      float gv = tanhf_(gpq);
      float gq = s8 * rintf(gv * i8v);
      float o = zf[rg] * h[rg];
      float n = (1.0f - zf[rg]) * gq;
      ov[rg] = o; nv[rg] = n;
      mo = fmaxf(mo, fabsf(o)); mn = fmaxf(mn, fabsf(n));
    }
    kk[0] = __float_as_uint(mo); kk[1] = __float_as_uint(mn);
    xchg<2>(kk, tag++, lred, gslot, wg, tid, lane);
    float s9  = fmaxf(__uint_as_float(kk[0]) / 127.0f, 1e-8f), i9  = 1.0f / s9;
    float s10 = fmaxf(__uint_as_float(kk[1]) / 127.0f, 1e-8f), i10 = 1.0f / s10;

    // ---- stage F: h_new, write output ----
    float mh = 0.0f;
    #pragma unroll
    for (int rg = 0; rg < 4; ++rg) {
      float oq = s9  * rintf(ov[rg] * i9);
      float nq = s10 * rintf(nv[rg] * i10);
      float hn = oq + nq;
      h[rg] = hn;
      mh = fmaxf(mh, fabsf(hn));
      out[t * 16384 + (brow + rg) * 256 + j] = hn;
    }
    kk[0] = __float_as_uint(mh);
    xchg<1>(kk, tag++, lred, gslot, wg, tid, lane);
    sh = fmaxf(__uint_as_float(kk[0]) / 127.0f, 1e-8f);
    float ish = 1.0f / sh;
    #pragma unroll
    for (int rg = 0; rg < 4; ++rg)
      ah[(lh * 4 + rg) * 272 + j] = (signed char)(int)rintf(h[rg] * ish);
    __syncthreads();                       // ah ready for next step (block-local)
  }

  // h_last
  #pragma unroll
  for (int rg = 0; rg < 4; ++rg)
    out[OUT_MAIN_FLOATS + (brow + rg) * 256 + j] = h[rg];
}

// ============================================================================
extern "C" void kernel_launch(void* const* d_in, const int* in_sizes, int n_in,
                              void* d_out, int out_size, void* d_ws, size_t ws_size,
                              hipStream_t stream) {
  const float* x   = (const float*)d_in[0];   // (1024,64,256)
  const float* wih = (const float*)d_in[1];   // (768,256)
  const float* whh = (const float*)d_in[2];   // (768,256)
  const float* bih = (const float*)d_in[3];   // (768,)
  const float* bhh = (const float*)d_in[4];   // (768,)
  const float* h0  = (const float*)d_in[5];   // (64,256)
  float* out = (float*)d_out;

  // d_ws layout: [0..255] absmax slots, [512..1023] tagged exchange slots
  // (2 parity x 4 wg x 8 ch x 8B), [4096..] bq, [10240..] fragment buffer F.
  unsigned* slots = (unsigned*)d_ws;
  unsigned long long* gslot = (unsigned long long*)((char*)d_ws + 512);
  float* bq       = (float*)((char*)d_ws + 4096);
  signed char* F  = (signed char*)d_ws + 10240;          // 196,608 B

  signed char* wxq = (signed char*)d_out + WXQ_DOUT_OFF; // tail of d_out
  signed char* xq8 = (signed char*)d_out;                // head (dead later)

  hipMemsetAsync(d_ws, 0, 4096, stream);

  k_absmax<<<dim3(1024), dim3(256), 0, stream>>>(x,   16777216 / 4, slots + 0);
  k_absmax<<<dim3(96),   dim3(256), 0, stream>>>(wih, 196608 / 4,   slots + 1);
  k_absmax<<<dim3(96),   dim3(256), 0, stream>>>(whh, 196608 / 4,   slots + 2);
  k_absmax<<<dim3(1),    dim3(256), 0, stream>>>(bih, 768 / 4,      slots + 3);
  k_absmax<<<dim3(1),    dim3(256), 0, stream>>>(bhh, 768 / 4,      slots + 4);

  k_frag<<<dim3(192), dim3(256), 0, stream>>>(wih, slots, 1, F);   // W frags
  k_bias<<<dim3(1), dim3(768), 0, stream>>>(bih, bhh, slots, bq);
  k_xq<<<dim3(16384), dim3(256), 0, stream>>>(x, slots, xq8, 4194304);

  k_wx_i8<<<dim3(1024), dim3(1024), 0, stream>>>(xq8, F, slots, wxq, 0);
  k_wx_i8<<<dim3(1024), dim3(1024), 0, stream>>>(xq8, F, slots, wxq, 1);

  k_frag<<<dim3(192), dim3(256), 0, stream>>>(whh, slots, 2, F);   // R frags

  k_recur4b<<<dim3(4), dim3(1024), 0, stream>>>(wxq, F, bq, slots, h0, out,
                                                gslot);
}